// Round 8
// baseline (354.305 us; speedup 1.0000x reference)
//
#include <hip/hip_runtime.h>
#include <hip/hip_cooperative_groups.h>

// QRNN: B=8 T=2048 C=512 U=512 W=2
// R8 = R7 cooperative fusion, hardened:
//  - __launch_bounds__(256,2) on qrnn_fused (VGPR<=256 -> 2 blocks/CU residency OK)
//  - hipLaunchCooperativeKernel return code CHECKED; on failure fall back to the
//    exact R6 five-kernel path (proven pass) in the same kernel_launch call.

namespace cg = cooperative_groups;

#define Bn 8
#define Tn 2048
#define Cn 512
#define Un 512
#define Nn 1536
#define Kn 1024
#define Mn (Bn * Tn)
#define NC 32
#define CL 64

using bf16x8 = __attribute__((ext_vector_type(8))) __bf16;
using f32x4  = __attribute__((ext_vector_type(4))) float;
using us8    = __attribute__((ext_vector_type(8))) unsigned short;

__device__ __forceinline__ void async16(const void* g, void* l) {
  __builtin_amdgcn_global_load_lds((const __attribute__((address_space(1))) void*)g,
                                   (__attribute__((address_space(3))) void*)l, 16, 0, 0);
}

__device__ __forceinline__ unsigned short f2bf(float v) {
  union { float f; unsigned u; } c; c.f = v;
  unsigned u = c.u;
  return (unsigned short)((u + 0x7fffu + ((u >> 16) & 1u)) >> 16);  // RNE
}
__device__ __forceinline__ float asf(unsigned u) {
  union { unsigned u; float f; } c; c.u = u; return c.f;
}
__device__ __forceinline__ float bf2f(unsigned short h) { return asf(((unsigned)h) << 16); }
__device__ __forceinline__ float bf_lo(unsigned w) { return asf(w << 16); }

__device__ __forceinline__ float fast_sigmoid(float x) {
  float e = __builtin_amdgcn_exp2f(-1.4426950408889634f * x);
  return __builtin_amdgcn_rcpf(1.0f + e);
}
__device__ __forceinline__ float fast_tanh(float x) {
  float e = __builtin_amdgcn_exp2f(-2.8853900817779268f * x);
  return 2.0f * __builtin_amdgcn_rcpf(1.0f + e) - 1.0f;
}

// ======================= fused cooperative kernel ===========================
__global__ __launch_bounds__(256, 2) void qrnn_fused(const float* __restrict__ x,
                                                     const float* __restrict__ kern,
                                                     const float* __restrict__ bias,
                                                     const float* __restrict__ init,
                                                     unsigned short* __restrict__ xb,
                                                     unsigned short* __restrict__ kT,
                                                     unsigned short* __restrict__ gates,
                                                     unsigned int* __restrict__ ab,
                                                     float* __restrict__ out) {
  cg::grid_group grid = cg::this_grid();
  __shared__ unsigned short As[128 * 64];   // 16 KB (aliased by conv_k tile)
  __shared__ unsigned short Bs[128 * 64];   // 16 KB
  const int tid = threadIdx.x;
  const int blk = blockIdx.x;               // 512 blocks

  // ---- stage 0a: conv_k -> kT bf16 [N][K] ----
  {
    float (*tileF)[33] = (float(*)[33])As;  // 32x33 fp32 = 4224 B
    int tx = tid & 31, ty = tid >> 5;
    for (int tile = blk; tile < 1536; tile += 512) {
      int kb = tile & 31, nb = tile >> 5;
#pragma unroll
      for (int i = 0; i < 4; i++)
        tileF[ty + i * 8][tx] = kern[(size_t)(kb * 32 + ty + i * 8) * Nn + nb * 32 + tx];
      __syncthreads();
#pragma unroll
      for (int i = 0; i < 4; i++)
        kT[(size_t)(nb * 32 + ty + i * 8) * Kn + kb * 32 + tx] = f2bf(tileF[tx][ty + i * 8]);
      __syncthreads();
    }
  }

  // ---- stage 0b: conv_x -> padded bf16 xb ----
  {
    const int total = Bn * (Tn + 1) * Cn / 8;  // 1,049,088
    for (int idx = blk * 256 + tid; idx < total; idx += 512 * 256) {
      int c8  = idx & 63;
      int row = idx >> 6;                   // b*(T+1)+t
      int b   = row / (Tn + 1);
      int t   = row - b * (Tn + 1);
      us8 ov;
      if (t == 0) {
        ov = (us8)0;
      } else {
        const float* src = x + (size_t)(b * Tn + t - 1) * Cn + c8 * 8;
        float4 v0 = *(const float4*)src;
        float4 v1 = *(const float4*)(src + 4);
        ov[0] = f2bf(v0.x); ov[1] = f2bf(v0.y); ov[2] = f2bf(v0.z); ov[3] = f2bf(v0.w);
        ov[4] = f2bf(v1.x); ov[5] = f2bf(v1.y); ov[6] = f2bf(v1.z); ov[7] = f2bf(v1.w);
      }
      *(us8*)(xb + (size_t)row * Cn + c8 * 8) = ov;
    }
  }

  grid.sync();

  // ---- stage 1: gemm, 3 tiles/block (R5-proven interior) ----
  {
    const int lane = tid & 63;
    const int w = tid >> 6, wr = w >> 1, wc = w & 1;
    const int my = blk & 127;               // constant per block -> A-tile reuse
    const int m0 = my * 128;
    const int batch = my >> 4;
    const int srow = (w << 3) + (lane >> 3);
    const int skq  = (lane & 7) ^ (lane >> 3);
    const unsigned short* aStage = xb + (size_t)(m0 + batch + srow) * Cn + (skq << 3);
    const int rA0 = wr * 64 + (lane & 15);
    const int rB0 = wc * 64 + (lane & 15);
    const int swz = lane & 7;

#pragma unroll 1
    for (int i = 0; i < 3; i++) {
      const int id = blk + 512 * i;
      const int ny = id >> 7;               // [0,12); region = ny>>2 == i
      const int n0 = ny * 128;
      const unsigned short* bStage = kT + (size_t)(n0 + srow) * Kn + (skq << 3);

      f32x4 zero = {0.f, 0.f, 0.f, 0.f};
      f32x4 acc[4][4];
#pragma unroll
      for (int a = 0; a < 4; a++)
#pragma unroll
        for (int b2 = 0; b2 < 4; b2++) acc[a][b2] = zero;

      for (int k0 = 0; k0 < Kn; k0 += 64) {
#pragma unroll
        for (int j = 0; j < 4; j++) {
          async16(aStage + (size_t)(j << 5) * Cn + k0, &As[(j * 256 + tid) * 8]);
          async16(bStage + (size_t)(j << 5) * Kn + k0, &Bs[(j * 256 + tid) * 8]);
        }
        __builtin_amdgcn_s_waitcnt(0);
        __syncthreads();
#pragma unroll
        for (int ks = 0; ks < 2; ks++) {
          const int col = (((ks << 2) + (lane >> 4)) ^ swz) << 3;
          bf16x8 af[4], bf[4];
#pragma unroll
          for (int a = 0; a < 4; a++) {
            af[a] = *(const bf16x8*)&As[(rA0 + a * 16) * 64 + col];
            bf[a] = *(const bf16x8*)&Bs[(rB0 + a * 16) * 64 + col];
          }
#pragma unroll
          for (int a = 0; a < 4; a++)
#pragma unroll
            for (int b2 = 0; b2 < 4; b2++)
              acc[a][b2] = __builtin_amdgcn_mfma_f32_16x16x32_bf16(af[a], bf[b2], acc[a][b2], 0, 0, 0);
        }
        __syncthreads();
      }

      const int rowB = wr * 64 + (lane >> 4) * 4;
      const int colB = wc * 64 + (lane & 15);
#pragma unroll
      for (int a = 0; a < 4; a++)
#pragma unroll
        for (int b2 = 0; b2 < 4; b2++)
#pragma unroll
          for (int r = 0; r < 4; r++) {
            int mm = m0 + rowB + a * 16 + r;
            int nn = n0 + colB + b2 * 16;
            float g = acc[a][b2][r] + bias[nn];
            float v = (i == 0) ? fast_tanh(g) : fast_sigmoid(g);
            gates[(size_t)mm * Nn + nn] = f2bf(v);
          }
    }
  }

  grid.sync();

  // ---- stage 2: phaseA ----
  {
    int chunk = blk >> 1;
    int u = (blk & 1) * 256 + tid;
    int b = chunk >> 5, c = chunk & (NC - 1);
    const unsigned short* gp = gates + (size_t)(b * Tn + c * CL) * Nn;
    float a = 1.0f, bv = 0.0f;
#pragma unroll 8
    for (int t = 0; t < CL; t++) {
      float z = bf2f(gp[u]);
      float f = bf2f(gp[Un + u]);
      a *= f;
      bv = f * bv + (1.0f - f) * z;
      gp += Nn;
    }
    ab[(size_t)chunk * Un + u] = ((unsigned)f2bf(a) << 16) | f2bf(bv);
  }

  grid.sync();

  // ---- stage 3: phaseC ----
  {
    int chunk = blk >> 1;
    int u = (blk & 1) * 256 + tid;
    int b = chunk >> 5, c = chunk & (NC - 1);
    float h = init[u];
    for (int cp = 0; cp < c; cp++) {
      unsigned wv = ab[(size_t)(b * NC + cp) * Un + u];
      h = asf(wv & 0xffff0000u) * h + bf_lo(wv);
    }
    const unsigned short* gp = gates + (size_t)(b * Tn + c * CL) * Nn;
    float* op = out + (size_t)(b * Tn + c * CL) * Un;
#pragma unroll 8
    for (int t = 0; t < CL; t++) {
      float z = bf2f(gp[u]);
      float f = bf2f(gp[Un + u]);
      float o = bf2f(gp[2 * Un + u]);
      h = f * h + (1.0f - f) * z;
      op[u] = h * o;
      gp += Nn;
      op += Un;
    }
  }
}

// ======================= R6 fallback kernels (proven) =======================
__global__ __launch_bounds__(256) void conv_x(const float* __restrict__ x,
                                              unsigned short* __restrict__ xb) {
  int idx = blockIdx.x * 256 + threadIdx.x;
  int c8  = idx & 63;
  int row = idx >> 6;
  int b   = row / (Tn + 1);
  int t   = row - b * (Tn + 1);
  us8 ov;
  if (t == 0) {
    ov = (us8)0;
  } else {
    const float* src = x + (size_t)(b * Tn + t - 1) * Cn + c8 * 8;
    float4 v0 = *(const float4*)src;
    float4 v1 = *(const float4*)(src + 4);
    ov[0] = f2bf(v0.x); ov[1] = f2bf(v0.y); ov[2] = f2bf(v0.z); ov[3] = f2bf(v0.w);
    ov[4] = f2bf(v1.x); ov[5] = f2bf(v1.y); ov[6] = f2bf(v1.z); ov[7] = f2bf(v1.w);
  }
  *(us8*)(xb + (size_t)row * Cn + c8 * 8) = ov;
}

__global__ __launch_bounds__(256) void conv_k(const float* __restrict__ kern,
                                              unsigned short* __restrict__ kT) {
  __shared__ float tile[32][33];
  int kb = blockIdx.x, nb = blockIdx.y;
  int tx = threadIdx.x & 31, ty = threadIdx.x >> 5;
#pragma unroll
  for (int i = 0; i < 4; i++)
    tile[ty + i * 8][tx] = kern[(size_t)(kb * 32 + ty + i * 8) * Nn + nb * 32 + tx];
  __syncthreads();
#pragma unroll
  for (int i = 0; i < 4; i++) {
    int n = nb * 32 + ty + i * 8;
    int k = kb * 32 + tx;
    kT[(size_t)n * Kn + k] = f2bf(tile[tx][ty + i * 8]);
  }
}

__global__ __launch_bounds__(256) void gemm_gates(const unsigned short* __restrict__ xb,
                                                  const unsigned short* __restrict__ kT,
                                                  const float* __restrict__ bias,
                                                  unsigned short* __restrict__ gates) {
  __shared__ unsigned short As[128 * 64];
  __shared__ unsigned short Bs[128 * 64];
  const int tid = threadIdx.x;
  const int m0 = blockIdx.x * 128;
  const int n0 = blockIdx.y * 128;
  const int batch = m0 / Tn;
  const int lane = tid & 63;
  const int w = tid >> 6, wr = w >> 1, wc = w & 1;

  const int srow = (w << 3) + (lane >> 3);
  const int skq  = (lane & 7) ^ (lane >> 3);
  const unsigned short* aStage = xb + (size_t)(m0 + batch + srow) * Cn + (skq << 3);
  const unsigned short* bStage = kT + (size_t)(n0 + srow) * Kn + (skq << 3);

  f32x4 zero = {0.f, 0.f, 0.f, 0.f};
  f32x4 acc[4][4];
#pragma unroll
  for (int i = 0; i < 4; i++)
#pragma unroll
    for (int j = 0; j < 4; j++) acc[i][j] = zero;

  const int rA0 = wr * 64 + (lane & 15);
  const int rB0 = wc * 64 + (lane & 15);
  const int swz = lane & 7;

  for (int k0 = 0; k0 < Kn; k0 += 64) {
#pragma unroll
    for (int j = 0; j < 4; j++) {
      async16(aStage + (size_t)(j << 5) * Cn + k0, &As[(j * 256 + tid) * 8]);
      async16(bStage + (size_t)(j << 5) * Kn + k0, &Bs[(j * 256 + tid) * 8]);
    }
    __builtin_amdgcn_s_waitcnt(0);
    __syncthreads();

#pragma unroll
    for (int ks = 0; ks < 2; ks++) {
      const int col = (((ks << 2) + (lane >> 4)) ^ swz) << 3;
      bf16x8 af[4], bf[4];
#pragma unroll
      for (int i = 0; i < 4; i++) {
        af[i] = *(const bf16x8*)&As[(rA0 + i * 16) * 64 + col];
        bf[i] = *(const bf16x8*)&Bs[(rB0 + i * 16) * 64 + col];
      }
#pragma unroll
      for (int i = 0; i < 4; i++)
#pragma unroll
        for (int j = 0; j < 4; j++)
          acc[i][j] = __builtin_amdgcn_mfma_f32_16x16x32_bf16(af[i], bf[j], acc[i][j], 0, 0, 0);
    }
    __syncthreads();
  }

  const int region = blockIdx.y >> 2;
  const int rowB = wr * 64 + (lane >> 4) * 4;
  const int colB = wc * 64 + (lane & 15);
#pragma unroll
  for (int i = 0; i < 4; i++)
#pragma unroll
    for (int j = 0; j < 4; j++)
#pragma unroll
      for (int r = 0; r < 4; r++) {
        int mm = m0 + rowB + i * 16 + r;
        int nn = n0 + colB + j * 16;
        float g = acc[i][j][r] + bias[nn];
        float a = (region == 0) ? fast_tanh(g) : fast_sigmoid(g);
        gates[(size_t)mm * Nn + nn] = f2bf(a);
      }
}

__global__ __launch_bounds__(256) void scan_phaseA(const unsigned short* __restrict__ gates,
                                                   unsigned int* __restrict__ ab) {
  int chunk = blockIdx.x >> 1;
  int u = (blockIdx.x & 1) * 256 + threadIdx.x;
  int b = chunk >> 5, c = chunk & (NC - 1);
  const unsigned short* gp = gates + (size_t)(b * Tn + c * CL) * Nn;
  float a = 1.0f, bv = 0.0f;
#pragma unroll 8
  for (int t = 0; t < CL; t++) {
    float z = bf2f(gp[u]);
    float f = bf2f(gp[Un + u]);
    a *= f;
    bv = f * bv + (1.0f - f) * z;
    gp += Nn;
  }
  ab[(size_t)chunk * Un + u] = ((unsigned)f2bf(a) << 16) | f2bf(bv);
}

__global__ __launch_bounds__(256) void scan_phaseC(const unsigned short* __restrict__ gates,
                                                   const unsigned int* __restrict__ ab,
                                                   const float* __restrict__ init,
                                                   float* __restrict__ out) {
  int chunk = blockIdx.x >> 1;
  int u = (blockIdx.x & 1) * 256 + threadIdx.x;
  int b = chunk >> 5, c = chunk & (NC - 1);
  float h = init[u];
  for (int cp = 0; cp < c; cp++) {
    unsigned wv = ab[(size_t)(b * NC + cp) * Un + u];
    h = asf(wv & 0xffff0000u) * h + bf_lo(wv);
  }
  const unsigned short* gp = gates + (size_t)(b * Tn + c * CL) * Nn;
  float* op = out + (size_t)(b * Tn + c * CL) * Un;
#pragma unroll 8
  for (int t = 0; t < CL; t++) {
    float z = bf2f(gp[u]);
    float f = bf2f(gp[Un + u]);
    float o = bf2f(gp[2 * Un + u]);
    h = f * h + (1.0f - f) * z;
    op[u] = h * o;
    gp += Nn;
    op += Un;
  }
}

extern "C" void kernel_launch(void* const* d_in, const int* in_sizes, int n_in,
                              void* d_out, int out_size, void* d_ws, size_t ws_size,
                              hipStream_t stream) {
  const float* x    = (const float*)d_in[0];  // [8,2048,512]
  const float* kern = (const float*)d_in[1];  // [2,512,1536]
  const float* bias = (const float*)d_in[2];  // [1536]
  const float* init = (const float*)d_in[3];  // [1,512]
  float* out = (float*)d_out;                 // [8,2048,512]

  char* ws = (char*)d_ws;
  unsigned short* xb = (unsigned short*)ws;                      // 16.8 MB
  size_t off = (size_t)Bn * (Tn + 1) * Cn * 2;
  unsigned short* kT = (unsigned short*)(ws + off);              // 3.1 MB
  off += (size_t)Nn * Kn * 2;
  unsigned short* gates = (unsigned short*)(ws + off);           // 50.3 MB (bf16)
  off += (size_t)Mn * Nn * 2;
  unsigned int* ab = (unsigned int*)(ws + off);                  // 512 KB

  void* args[] = {(void*)&x, (void*)&kern, (void*)&bias, (void*)&init,
                  (void*)&xb, (void*)&kT, (void*)&gates, (void*)&ab, (void*)&out};
  hipError_t e = hipLaunchCooperativeKernel(qrnn_fused, dim3(512), dim3(256),
                                            args, 0, stream);
  if (e != hipSuccess) {
    // deterministic fallback: proven R6 five-kernel path
    conv_x<<<(Bn * (Tn + 1) * Cn / 8) / 256, 256, 0, stream>>>(x, xb);
    conv_k<<<dim3(32, 48), 256, 0, stream>>>(kern, kT);
    gemm_gates<<<dim3(Mn / 128, Nn / 128), 256, 0, stream>>>(xb, kT, bias, gates);
    scan_phaseA<<<Bn * NC * 2, 256, 0, stream>>>(gates, ab);
    scan_phaseC<<<Bn * NC * 2, 256, 0, stream>>>(gates, ab, init, out);
  }
}

// Round 9
// 254.349 us; speedup vs baseline: 1.3930x; 1.3930x over previous
//
#include <hip/hip_runtime.h>

// QRNN: B=8 T=2048 C=512 U=512 W=2
// R9: 3-kernel recomposition of R8-proven pieces (boundaries 5 -> 2):
//  1. prep: conv_k (blocks 0..1535) + conv_x (blocks 1536..5633) by grid partition
//  2. gemm3_scan: grid (128 m, 4 nsub); block runs z/f/o 128x128 tiles serially
//     (R5 K-loop), stashes activated z,f in LDS, computes phaseA for its 2 chunks
//     in-block -> packed ab[]. LDS 64KB (As16+Bs16+Zs32; Fs overlays As/Bs).
//  3. phaseC: R6-proven (512 blocks, in-block prefix from ab[]).

#define Bn 8
#define Tn 2048
#define Cn 512
#define Un 512
#define Nn 1536
#define Kn 1024
#define Mn (Bn * Tn)
#define NC 32
#define CL 64

using bf16x8 = __attribute__((ext_vector_type(8))) __bf16;
using f32x4  = __attribute__((ext_vector_type(4))) float;
using us8    = __attribute__((ext_vector_type(8))) unsigned short;

__device__ __forceinline__ void async16(const void* g, void* l) {
  __builtin_amdgcn_global_load_lds((const __attribute__((address_space(1))) void*)g,
                                   (__attribute__((address_space(3))) void*)l, 16, 0, 0);
}

__device__ __forceinline__ unsigned short f2bf(float v) {
  union { float f; unsigned u; } c; c.f = v;
  unsigned u = c.u;
  return (unsigned short)((u + 0x7fffu + ((u >> 16) & 1u)) >> 16);  // RNE
}
__device__ __forceinline__ float asf(unsigned u) {
  union { unsigned u; float f; } c; c.u = u; return c.f;
}
__device__ __forceinline__ float bf2f(unsigned short h) { return asf(((unsigned)h) << 16); }
__device__ __forceinline__ float bf_lo(unsigned w) { return asf(w << 16); }

__device__ __forceinline__ float fast_sigmoid(float x) {
  float e = __builtin_amdgcn_exp2f(-1.4426950408889634f * x);
  return __builtin_amdgcn_rcpf(1.0f + e);
}
__device__ __forceinline__ float fast_tanh(float x) {
  float e = __builtin_amdgcn_exp2f(-2.8853900817779268f * x);
  return 2.0f * __builtin_amdgcn_rcpf(1.0f + e) - 1.0f;
}

// ---- 1. prep: conv_k (tiles 0..1535) + conv_x (rest) ------------------------
__global__ __launch_bounds__(256) void prep(const float* __restrict__ x,
                                            const float* __restrict__ kern,
                                            unsigned short* __restrict__ xb,
                                            unsigned short* __restrict__ kT) {
  __shared__ float tile[32][33];
  const int tid = threadIdx.x;
  if (blockIdx.x < 1536) {
    // conv_k: kernel fp32 [1024,1536] -> kT bf16 [1536,1024]
    int kb = blockIdx.x & 31, nb = blockIdx.x >> 5;
    int tx = tid & 31, ty = tid >> 5;
#pragma unroll
    for (int i = 0; i < 4; i++)
      tile[ty + i * 8][tx] = kern[(size_t)(kb * 32 + ty + i * 8) * Nn + nb * 32 + tx];
    __syncthreads();
#pragma unroll
    for (int i = 0; i < 4; i++) {
      int n = nb * 32 + ty + i * 8;
      int k = kb * 32 + tx;
      kT[(size_t)n * Kn + k] = f2bf(tile[tx][ty + i * 8]);
    }
  } else {
    // conv_x: x fp32 [B,T,C] -> xb bf16 [B,T+1,C], row t=0 zeroed
    int idx = (blockIdx.x - 1536) * 256 + tid;   // [0, 1049088)
    int c8  = idx & 63;
    int row = idx >> 6;
    int b   = row / (Tn + 1);
    int t   = row - b * (Tn + 1);
    us8 ov;
    if (t == 0) {
      ov = (us8)0;
    } else {
      const float* src = x + (size_t)(b * Tn + t - 1) * Cn + c8 * 8;
      float4 v0 = *(const float4*)src;
      float4 v1 = *(const float4*)(src + 4);
      ov[0] = f2bf(v0.x); ov[1] = f2bf(v0.y); ov[2] = f2bf(v0.z); ov[3] = f2bf(v0.w);
      ov[4] = f2bf(v1.x); ov[5] = f2bf(v1.y); ov[6] = f2bf(v1.z); ov[7] = f2bf(v1.w);
    }
    *(us8*)(xb + (size_t)row * Cn + c8 * 8) = ov;
  }
}

// ---- 2. gemm3 + in-block phaseA ---------------------------------------------
// grid (128 m-tiles, 4 nsub). Block: 3 serial 128x128 tiles (z,f,o) with the
// R5-proven K-loop; z,f stashed in LDS; phaseA for the block's 2 chunks x 128 u.
__global__ __launch_bounds__(256) void gemm3_scan(const unsigned short* __restrict__ xb,
                                                  const unsigned short* __restrict__ kT,
                                                  const float* __restrict__ bias,
                                                  unsigned short* __restrict__ gates,
                                                  unsigned int* __restrict__ ab) {
  __shared__ unsigned short As[128 * 64];   // 16 KB
  __shared__ unsigned short Bs[128 * 64];   // 16 KB
  __shared__ unsigned short Zs[128 * 128];  // 32 KB z stash
  unsigned short* Fs = As;                  // f stash overlays As+Bs (32 KB contiguous)

  const int tid = threadIdx.x;
  const int my = blockIdx.x;                // [0,128)
  const int nsub = blockIdx.y;              // [0,4)
  const int m0 = my * 128;
  const int batch = my >> 4;
  const int lane = tid & 63;
  const int w = tid >> 6, wr = w >> 1, wc = w & 1;

  const int srow = (w << 3) + (lane >> 3);
  const int skq  = (lane & 7) ^ (lane >> 3);
  const unsigned short* aStage = xb + (size_t)(m0 + batch + srow) * Cn + (skq << 3);
  const int rA0 = wr * 64 + (lane & 15);
  const int rB0 = wc * 64 + (lane & 15);
  const int swz = lane & 7;
  const int rowB = wr * 64 + (lane >> 4) * 4;
  const int colB = wc * 64 + (lane & 15);

#pragma unroll 1
  for (int reg = 0; reg < 3; reg++) {
    const int n0 = reg * 512 + nsub * 128;
    const unsigned short* bStage = kT + (size_t)(n0 + srow) * Kn + (skq << 3);

    f32x4 zero = {0.f, 0.f, 0.f, 0.f};
    f32x4 acc[4][4];
#pragma unroll
    for (int i = 0; i < 4; i++)
#pragma unroll
      for (int j = 0; j < 4; j++) acc[i][j] = zero;

    for (int k0 = 0; k0 < Kn; k0 += 64) {
#pragma unroll
      for (int j = 0; j < 4; j++) {
        async16(aStage + (size_t)(j << 5) * Cn + k0, &As[(j * 256 + tid) * 8]);
        async16(bStage + (size_t)(j << 5) * Kn + k0, &Bs[(j * 256 + tid) * 8]);
      }
      __builtin_amdgcn_s_waitcnt(0);
      __syncthreads();

#pragma unroll
      for (int ks = 0; ks < 2; ks++) {
        const int col = (((ks << 2) + (lane >> 4)) ^ swz) << 3;
        bf16x8 af[4], bf[4];
#pragma unroll
        for (int i = 0; i < 4; i++) {
          af[i] = *(const bf16x8*)&As[(rA0 + i * 16) * 64 + col];
          bf[i] = *(const bf16x8*)&Bs[(rB0 + i * 16) * 64 + col];
        }
#pragma unroll
        for (int i = 0; i < 4; i++)
#pragma unroll
          for (int j = 0; j < 4; j++)
            acc[i][j] = __builtin_amdgcn_mfma_f32_16x16x32_bf16(af[i], bf[j], acc[i][j], 0, 0, 0);
      }
      __syncthreads();
    }

    // epilogue: write gates; stash z (reg0) / f (reg1) into LDS
#pragma unroll
    for (int i = 0; i < 4; i++)
#pragma unroll
      for (int j = 0; j < 4; j++)
#pragma unroll
        for (int r = 0; r < 4; r++) {
          int rl = rowB + i * 16 + r;       // local row [0,128)
          int ul = colB + j * 16;           // local col [0,128)
          int mm = m0 + rl;
          int nn = n0 + ul;
          float g = acc[i][j][r] + bias[nn];
          float a = (reg == 0) ? fast_tanh(g) : fast_sigmoid(g);
          unsigned short hb = f2bf(a);
          gates[(size_t)mm * Nn + nn] = hb;
          if (reg == 0) Zs[rl * 128 + ul] = hb;
          else if (reg == 1) Fs[rl * 128 + ul] = hb;
        }

    if (reg == 1) {
      __syncthreads();                      // Fs/Zs fully written
      // phaseA for this block's 2 chunks x 128 u
      int u  = tid & 127;
      int ch = tid >> 7;                    // 0 or 1
      float a = 1.0f, bv = 0.0f;
#pragma unroll 8
      for (int t = 0; t < CL; t++) {
        float z = bf2f(Zs[(ch * 64 + t) * 128 + u]);
        float f = bf2f(Fs[(ch * 64 + t) * 128 + u]);
        a *= f;
        bv = f * bv + (1.0f - f) * z;
      }
      int cglob = (my & 15) * 2 + ch;       // chunk within batch
      ab[(size_t)(batch * NC + cglob) * Un + nsub * 128 + u] =
          ((unsigned)f2bf(a) << 16) | f2bf(bv);
      __syncthreads();                      // before o-tile re-stages As/Bs
    }
  }
}

// ---- 3. phaseC: replay with in-block prefix (R6-proven) ---------------------
__global__ __launch_bounds__(256) void scan_phaseC(const unsigned short* __restrict__ gates,
                                                   const unsigned int* __restrict__ ab,
                                                   const float* __restrict__ init,
                                                   float* __restrict__ out) {
  int chunk = blockIdx.x >> 1;
  int u = (blockIdx.x & 1) * 256 + threadIdx.x;
  int b = chunk >> 5, c = chunk & (NC - 1);
  float h = init[u];
  for (int cp = 0; cp < c; cp++) {
    unsigned wv = ab[(size_t)(b * NC + cp) * Un + u];
    h = asf(wv & 0xffff0000u) * h + bf_lo(wv);
  }
  const unsigned short* gp = gates + (size_t)(b * Tn + c * CL) * Nn;
  float* op = out + (size_t)(b * Tn + c * CL) * Un;
#pragma unroll 8
  for (int t = 0; t < CL; t++) {
    float z = bf2f(gp[u]);
    float f = bf2f(gp[Un + u]);
    float o = bf2f(gp[2 * Un + u]);
    h = f * h + (1.0f - f) * z;
    op[u] = h * o;
    gp += Nn;
    op += Un;
  }
}

extern "C" void kernel_launch(void* const* d_in, const int* in_sizes, int n_in,
                              void* d_out, int out_size, void* d_ws, size_t ws_size,
                              hipStream_t stream) {
  const float* x    = (const float*)d_in[0];  // [8,2048,512]
  const float* kern = (const float*)d_in[1];  // [2,512,1536]
  const float* bias = (const float*)d_in[2];  // [1536]
  const float* init = (const float*)d_in[3];  // [1,512]
  float* out = (float*)d_out;                 // [8,2048,512]

  char* ws = (char*)d_ws;
  unsigned short* xb = (unsigned short*)ws;                      // 16.8 MB
  size_t off = (size_t)Bn * (Tn + 1) * Cn * 2;
  unsigned short* kT = (unsigned short*)(ws + off);              // 3.1 MB
  off += (size_t)Nn * Kn * 2;
  unsigned short* gates = (unsigned short*)(ws + off);           // 50.3 MB (bf16)
  off += (size_t)Mn * Nn * 2;
  unsigned int* ab = (unsigned int*)(ws + off);                  // 512 KB

  prep<<<1536 + (Bn * (Tn + 1) * Cn / 8) / 256, 256, 0, stream>>>(x, kern, xb, kT);
  gemm3_scan<<<dim3(128, 4), 256, 0, stream>>>(xb, kT, bias, gates, ab);
  scan_phaseC<<<Bn * NC * 2, 256, 0, stream>>>(gates, ab, init, out);
}

// Round 10
// 184.322 us; speedup vs baseline: 1.9222x; 1.3799x over previous
//
#include <hip/hip_runtime.h>

// QRNN: B=8 T=2048 C=512 U=512 W=2
// R10: floor-chasing recomposition of proven parts:
//  - prep: R9-exact (conv_k blocks 0..1535, conv_x rest).
//  - gemm: R5-exact K-loop; grid transposed to (12 n, 128 m) so consecutive
//    blocks share the A-tile (L2-hot); epilogue stores RAW bias-added gates
//    (bf16) -- no activation in the VALU-bound gemm.
//  - phaseA (R6 shape) / phaseC (R9 shape) apply tanh/sigmoid on the fly;
//    they are memory-bound with idle VALU, so activations are free there.
// Known fixed costs: ~80 us/replay harness restore+poison (measured R8:
// single-kernel interior 272 vs wall 354); gemm structural plateau ~31-34%
// MfmaUtil (m97-class 2-barrier K-loop).

#define Bn 8
#define Tn 2048
#define Cn 512
#define Un 512
#define Nn 1536
#define Kn 1024
#define Mn (Bn * Tn)
#define NC 32
#define CL 64

using bf16x8 = __attribute__((ext_vector_type(8))) __bf16;
using f32x4  = __attribute__((ext_vector_type(4))) float;
using us8    = __attribute__((ext_vector_type(8))) unsigned short;

__device__ __forceinline__ void async16(const void* g, void* l) {
  __builtin_amdgcn_global_load_lds((const __attribute__((address_space(1))) void*)g,
                                   (__attribute__((address_space(3))) void*)l, 16, 0, 0);
}

__device__ __forceinline__ unsigned short f2bf(float v) {
  union { float f; unsigned u; } c; c.f = v;
  unsigned u = c.u;
  return (unsigned short)((u + 0x7fffu + ((u >> 16) & 1u)) >> 16);  // RNE
}
__device__ __forceinline__ float asf(unsigned u) {
  union { unsigned u; float f; } c; c.u = u; return c.f;
}
__device__ __forceinline__ float bf2f(unsigned short h) { return asf(((unsigned)h) << 16); }
__device__ __forceinline__ float bf_lo(unsigned w) { return asf(w << 16); }
__device__ __forceinline__ float bf_hi(unsigned w) { return asf(w & 0xffff0000u); }

__device__ __forceinline__ float fast_sigmoid(float x) {
  float e = __builtin_amdgcn_exp2f(-1.4426950408889634f * x);
  return __builtin_amdgcn_rcpf(1.0f + e);
}
__device__ __forceinline__ float fast_tanh(float x) {
  float e = __builtin_amdgcn_exp2f(-2.8853900817779268f * x);
  return 2.0f * __builtin_amdgcn_rcpf(1.0f + e) - 1.0f;
}

// ---- 1. prep: conv_k (tiles 0..1535) + conv_x (rest) [R9-proven] ------------
__global__ __launch_bounds__(256) void prep(const float* __restrict__ x,
                                            const float* __restrict__ kern,
                                            unsigned short* __restrict__ xb,
                                            unsigned short* __restrict__ kT) {
  __shared__ float tile[32][33];
  const int tid = threadIdx.x;
  if (blockIdx.x < 1536) {
    int kb = blockIdx.x & 31, nb = blockIdx.x >> 5;
    int tx = tid & 31, ty = tid >> 5;
#pragma unroll
    for (int i = 0; i < 4; i++)
      tile[ty + i * 8][tx] = kern[(size_t)(kb * 32 + ty + i * 8) * Nn + nb * 32 + tx];
    __syncthreads();
#pragma unroll
    for (int i = 0; i < 4; i++) {
      int n = nb * 32 + ty + i * 8;
      int k = kb * 32 + tx;
      kT[(size_t)n * Kn + k] = f2bf(tile[tx][ty + i * 8]);
    }
  } else {
    int idx = (blockIdx.x - 1536) * 256 + tid;   // [0, 1049088)
    int c8  = idx & 63;
    int row = idx >> 6;
    int b   = row / (Tn + 1);
    int t   = row - b * (Tn + 1);
    us8 ov;
    if (t == 0) {
      ov = (us8)0;
    } else {
      const float* src = x + (size_t)(b * Tn + t - 1) * Cn + c8 * 8;
      float4 v0 = *(const float4*)src;
      float4 v1 = *(const float4*)(src + 4);
      ov[0] = f2bf(v0.x); ov[1] = f2bf(v0.y); ov[2] = f2bf(v0.z); ov[3] = f2bf(v0.w);
      ov[4] = f2bf(v1.x); ov[5] = f2bf(v1.y); ov[6] = f2bf(v1.z); ov[7] = f2bf(v1.w);
    }
    *(us8*)(xb + (size_t)row * Cn + c8 * 8) = ov;
  }
}

// ---- 2. MFMA GEMM, raw-gate epilogue (R5 K-loop) ----------------------------
// grid (12 n-tiles, 128 m-tiles): consecutive blocks share the A-tile.
__global__ __launch_bounds__(256) void gemm_gates(const unsigned short* __restrict__ xb,
                                                  const unsigned short* __restrict__ kT,
                                                  const float* __restrict__ bias,
                                                  unsigned short* __restrict__ gates) {
  __shared__ unsigned short As[128 * 64];   // 16 KB
  __shared__ unsigned short Bs[128 * 64];   // 16 KB
  const int tid = threadIdx.x;
  const int m0 = blockIdx.y * 128;
  const int n0 = blockIdx.x * 128;
  const int batch = blockIdx.y >> 4;        // tiles never cross batch
  const int lane = tid & 63;
  const int w = tid >> 6, wr = w >> 1, wc = w & 1;

  const int srow = (w << 3) + (lane >> 3);
  const int skq  = (lane & 7) ^ (lane >> 3);
  const unsigned short* aStage = xb + (size_t)(m0 + batch + srow) * Cn + (skq << 3);
  const unsigned short* bStage = kT + (size_t)(n0 + srow) * Kn + (skq << 3);

  f32x4 zero = {0.f, 0.f, 0.f, 0.f};
  f32x4 acc[4][4];
#pragma unroll
  for (int i = 0; i < 4; i++)
#pragma unroll
    for (int j = 0; j < 4; j++) acc[i][j] = zero;

  const int rA0 = wr * 64 + (lane & 15);
  const int rB0 = wc * 64 + (lane & 15);
  const int swz = lane & 7;

  for (int k0 = 0; k0 < Kn; k0 += 64) {
#pragma unroll
    for (int j = 0; j < 4; j++) {
      async16(aStage + (size_t)(j << 5) * Cn + k0, &As[(j * 256 + tid) * 8]);
      async16(bStage + (size_t)(j << 5) * Kn + k0, &Bs[(j * 256 + tid) * 8]);
    }
    __builtin_amdgcn_s_waitcnt(0);
    __syncthreads();

#pragma unroll
    for (int ks = 0; ks < 2; ks++) {
      const int col = (((ks << 2) + (lane >> 4)) ^ swz) << 3;
      bf16x8 af[4], bf[4];
#pragma unroll
      for (int i = 0; i < 4; i++) {
        af[i] = *(const bf16x8*)&As[(rA0 + i * 16) * 64 + col];
        bf[i] = *(const bf16x8*)&Bs[(rB0 + i * 16) * 64 + col];
      }
#pragma unroll
      for (int i = 0; i < 4; i++)
#pragma unroll
        for (int j = 0; j < 4; j++)
          acc[i][j] = __builtin_amdgcn_mfma_f32_16x16x32_bf16(af[i], bf[j], acc[i][j], 0, 0, 0);
    }
    __syncthreads();
  }

  // epilogue: raw bias-added gate, bf16, NO activation (moved to scans)
  const int rowB = wr * 64 + (lane >> 4) * 4;
  const int colB = wc * 64 + (lane & 15);
#pragma unroll
  for (int i = 0; i < 4; i++)
#pragma unroll
    for (int j = 0; j < 4; j++)
#pragma unroll
      for (int r = 0; r < 4; r++) {
        int mm = m0 + rowB + i * 16 + r;
        int nn = n0 + colB + j * 16;
        gates[(size_t)mm * Nn + nn] = f2bf(acc[i][j][r] + bias[nn]);
      }
}

// ---- 3. phaseA: per-chunk (a,bv), activations on the fly [R6 shape] ---------
__global__ __launch_bounds__(256) void scan_phaseA(const unsigned short* __restrict__ gates,
                                                   unsigned int* __restrict__ ab) {
  int chunk = blockIdx.x;                   // 256 blocks
  int b = chunk >> 5, c = chunk & (NC - 1);
  int u2 = threadIdx.x * 2;
  const unsigned short* gp = gates + (size_t)(b * Tn + c * CL) * Nn;
  float a0 = 1.f, a1 = 1.f, bv0 = 0.f, bv1 = 0.f;
#pragma unroll 8
  for (int t = 0; t < CL; t++) {
    unsigned zz = *(const unsigned*)(gp + u2);
    unsigned ff = *(const unsigned*)(gp + Un + u2);
    float z0 = fast_tanh(bf_lo(zz)), z1 = fast_tanh(bf_hi(zz));
    float f0 = fast_sigmoid(bf_lo(ff)), f1 = fast_sigmoid(bf_hi(ff));
    a0 *= f0; a1 *= f1;
    bv0 = f0 * bv0 + (1.0f - f0) * z0;
    bv1 = f1 * bv1 + (1.0f - f1) * z1;
    gp += Nn;
  }
  uint2 w;
  w.x = ((unsigned)f2bf(a0) << 16) | f2bf(bv0);
  w.y = ((unsigned)f2bf(a1) << 16) | f2bf(bv1);
  *(uint2*)(ab + (size_t)chunk * Un + u2) = w;
}

// ---- 4. phaseC: in-block prefix + replay, activations on the fly [R9 shape] -
__global__ __launch_bounds__(256) void scan_phaseC(const unsigned short* __restrict__ gates,
                                                   const unsigned int* __restrict__ ab,
                                                   const float* __restrict__ init,
                                                   float* __restrict__ out) {
  int chunk = blockIdx.x >> 1;              // 512 blocks
  int u = (blockIdx.x & 1) * 256 + threadIdx.x;
  int b = chunk >> 5, c = chunk & (NC - 1);
  float h = init[u];
  for (int cp = 0; cp < c; cp++) {
    unsigned wv = ab[(size_t)(b * NC + cp) * Un + u];
    h = asf(wv & 0xffff0000u) * h + bf_lo(wv);
  }
  const unsigned short* gp = gates + (size_t)(b * Tn + c * CL) * Nn;
  float* op = out + (size_t)(b * Tn + c * CL) * Un;
#pragma unroll 8
  for (int t = 0; t < CL; t++) {
    float z = fast_tanh(bf2f(gp[u]));
    float f = fast_sigmoid(bf2f(gp[Un + u]));
    float o = fast_sigmoid(bf2f(gp[2 * Un + u]));
    h = f * h + (1.0f - f) * z;
    op[u] = h * o;
    gp += Nn;
    op += Un;
  }
}

extern "C" void kernel_launch(void* const* d_in, const int* in_sizes, int n_in,
                              void* d_out, int out_size, void* d_ws, size_t ws_size,
                              hipStream_t stream) {
  const float* x    = (const float*)d_in[0];  // [8,2048,512]
  const float* kern = (const float*)d_in[1];  // [2,512,1536]
  const float* bias = (const float*)d_in[2];  // [1536]
  const float* init = (const float*)d_in[3];  // [1,512]
  float* out = (float*)d_out;                 // [8,2048,512]

  char* ws = (char*)d_ws;
  unsigned short* xb = (unsigned short*)ws;                      // 16.8 MB
  size_t off = (size_t)Bn * (Tn + 1) * Cn * 2;
  unsigned short* kT = (unsigned short*)(ws + off);              // 3.1 MB
  off += (size_t)Nn * Kn * 2;
  unsigned short* gates = (unsigned short*)(ws + off);           // 50.3 MB (bf16, raw)
  off += (size_t)Mn * Nn * 2;
  unsigned int* ab = (unsigned int*)(ws + off);                  // 512 KB

  prep<<<1536 + (Bn * (Tn + 1) * Cn / 8) / 256, 256, 0, stream>>>(x, kern, xb, kT);
  gemm_gates<<<dim3(Nn / 128, Mn / 128), 256, 0, stream>>>(xb, kT, bias, gates);
  scan_phaseA<<<Bn * NC, 256, 0, stream>>>(gates, ab);
  scan_phaseC<<<Bn * NC * 2, 256, 0, stream>>>(gates, ab, init, out);
}